// Round 4
// baseline (2004.179 us; speedup 1.0000x reference)
//
#include <hip/hip_runtime.h>
#include <stdint.h>

static constexpr float kThresh = 0.3f;
static constexpr int N   = 2048;     // detections per batch (fixed by problem)
static constexpr int NT  = 256;      // threads per block (4 waves)
static constexpr int LPT = N / NT;   // 8 elements loaded/output per thread
static constexpr int E   = 8;        // max active slots per thread
static constexpr int NW  = NT / 64;  // 4 waves

using u64 = unsigned long long;
using u32 = unsigned int;

// ---- wave max of f32 via DPP (validated r2): lane 63 ends with the max ----
template <int CTRL>
__device__ __forceinline__ float dpp_fmax_step(float v) {
    const int m = __builtin_amdgcn_update_dpp(__float_as_int(v), __float_as_int(v),
                                              CTRL, 0xF, 0xF, false);
    return fmaxf(v, __int_as_float(m));
}
__device__ __forceinline__ float wave_fmax(float v) {
    v = dpp_fmax_step<0x111>(v);   // row_shr:1
    v = dpp_fmax_step<0x112>(v);   // row_shr:2
    v = dpp_fmax_step<0x114>(v);   // row_shr:4
    v = dpp_fmax_step<0x118>(v);   // row_shr:8
    v = dpp_fmax_step<0x142>(v);   // row_bcast:15
    v = dpp_fmax_step<0x143>(v);   // row_bcast:31
    return __int_as_float(__builtin_amdgcn_readlane(__float_as_int(v), 63));
}

// ---- u64 max fallback (validated r3) for exact-score ties ----
template <int CTRL>
__device__ __forceinline__ u64 dpp_max_u64_step(u64 k) {
    const int lo  = (int)(u32)k;
    const int hi  = (int)(u32)(k >> 32);
    const int mlo = __builtin_amdgcn_update_dpp(lo, lo, CTRL, 0xF, 0xF, false);
    const int mhi = __builtin_amdgcn_update_dpp(hi, hi, CTRL, 0xF, 0xF, false);
    const u64 m   = ((u64)(u32)mhi << 32) | (u32)mlo;
    return (m > k) ? m : k;
}
__device__ __forceinline__ u64 wave_max_u64(u64 k) {
    k = dpp_max_u64_step<0x111>(k);
    k = dpp_max_u64_step<0x112>(k);
    k = dpp_max_u64_step<0x114>(k);
    k = dpp_max_u64_step<0x118>(k);
    k = dpp_max_u64_step<0x142>(k);
    k = dpp_max_u64_step<0x143>(k);
    const int lo = __builtin_amdgcn_readlane((int)(u32)k, 63);
    const int hi = __builtin_amdgcn_readlane((int)(u32)(k >> 32), 63);
    return ((u64)(u32)hi << 32) | (u32)lo;
}

// key: (s_bits+1)<<32 | (2047-j)<<11 | pos.  s>=0 => monotone; +1 makes any
// active element (even score 0.0) beat the empty key 0; equal scores ->
// larger (2047-j) wins = LOWEST index (exactly jnp.argmax). j unique.
__device__ __forceinline__ u64 make_key(float s, int j, int pos) {
    return (((u64)(__float_as_uint(s) + 1u)) << 32)
         | (u64)(u32)(((N - 1 - j) << 11) | pos);
}

// Per-wave pick + LDS publish. Uniform control flow across the wave.
__device__ __forceinline__ void wave_pick_write(float sbest, int jbest, int posbest,
                                                float4 kbox, float karea, int lane,
                                                u64* redkSlot, float4* payASlot,
                                                float* payBSlot) {
    const float wmax = wave_fmax(sbest);
    if (wmax < 0.0f) {                       // whole wave inactive
        if (lane == 0) *redkSlot = 0ULL;     // never leave a stale key
        return;
    }
    const u64 mask = __ballot(sbest == wmax);
    if (__popcll(mask) == 1) {               // common path: unique winner lane
        if (sbest == wmax) {
            *redkSlot = make_key(sbest, jbest, posbest);
            *payASlot = kbox;
            *payBSlot = karea;
        }
    } else {                                 // rare: exact score tie -> u64 reduce
        const u64 kk = (sbest == wmax) ? make_key(sbest, jbest, posbest) : 0ULL;
        const u64 wm = wave_max_u64(kk);
        if (kk == wm && kk != 0ULL) {
            *redkSlot = kk;
            *payASlot = kbox;
            *payBSlot = karea;
        }
    }
}

__launch_bounds__(NT, 1)
__global__ void soft_nms_kernel(const float* __restrict__ det,
                                float* __restrict__ out, int B) {
    const int b    = blockIdx.x;
    const int t    = threadIdx.x;
    const int lane = t & 63;
    const int wid  = t >> 6;

    __shared__ float4 sbox[N];      // static after prologue
    __shared__ float  sfin[N];      // initial score (valid) / -1; later picked value
    __shared__ int    slist[N];     // prologue-only compaction scratch
    __shared__ int    swave[NW];
    __shared__ u64    redk[2][NW];  // per-wave winner keys (parity dbuf)
    __shared__ float4 spayA[2][NW]; // per-wave winner box
    __shared__ float  spayB[2][NW]; // per-wave winner area
    __shared__ float4 smovA[2];     // moved-element box (slot m-1)
    __shared__ float4 smovB[2];     // (area, decayed score, j bits, 0)

    const float* dbase = det + (size_t)b * N * 5;

    // ---------------- prologue: load, classify, compact ----------------
    int lval = 0, c = 0;
    #pragma unroll
    for (int e = 0; e < LPT; ++e) {
        const int j = t * LPT + e;
        const float* p = dbase + (size_t)j * 5;
        const float x1 = p[0], y1 = p[1], x2 = p[2], y2 = p[3], sc = p[4];
        sbox[j] = make_float4(x1, y1, x2, y2);
        const int va = sc > kThresh;
        sfin[j] = va ? sc : -1.0f;   // carries score until picked; -1 if invalid
        lval |= va << e;
        c += va;
    }
    int pfx = c;                                  // wave-inclusive prefix
    #pragma unroll
    for (int d = 1; d < 64; d <<= 1) {
        const int v = __shfl_up(pfx, d, 64);
        if (lane >= d) pfx += v;
    }
    if (lane == 63) swave[wid] = pfx;
    __syncthreads();                              // P1

    int wbase = 0, n0 = 0;
    #pragma unroll
    for (int w = 0; w < NW; ++w) {
        const int v = swave[w];
        if (w < wid) wbase += v;
        n0 += v;
    }
    int mypos = wbase + (pfx - c);
    #pragma unroll
    for (int e = 0; e < LPT; ++e)
        if ((lval >> e) & 1) slist[mypos++] = t * LPT + e;
    __syncthreads();                              // P2

    // ---- register slots: thread t owns positions t, t+NT, ... ----
    int   jr[E]; float sr[E];
    float bx1[E], by1[E], bx2[E], by2[E], bar[E];
    float  sbest = -1.0f; int jbest = 0, posbest = 0;
    float4 kbox  = make_float4(0.f, 0.f, 0.f, 0.f);
    float  karea = 0.0f;

    #pragma unroll
    for (int e = 0; e < E; ++e) {
        jr[e] = 0; sr[e] = -1.0f;
        bx1[e] = by1[e] = bx2[e] = by2[e] = bar[e] = 0.0f;
        const int pos = t + NT * e;
        if (pos < n0) {
            const int j = slist[pos];
            jr[e] = j; sr[e] = sfin[j];
            const float4 bb = sbox[j];
            bx1[e] = bb.x; by1[e] = bb.y; bx2[e] = bb.z; by2[e] = bb.w;
            bar[e] = (bb.z - bb.x + 1.0f) * (bb.w - bb.y + 1.0f);
            if (pos == n0 - 1) {
                smovA[1] = bb;
                smovB[1] = make_float4(bar[e], sr[e], __int_as_float(j), 0.0f);
            }
            const bool bt = (sr[e] > sbest) || (sr[e] == sbest && j < jbest);
            sbest   = bt ? sr[e] : sbest;
            jbest   = bt ? j     : jbest;
            posbest = bt ? pos   : posbest;
            kbox.x  = bt ? bx1[e] : kbox.x;  kbox.y = bt ? by1[e] : kbox.y;
            kbox.z  = bt ? bx2[e] : kbox.z;  kbox.w = bt ? by2[e] : kbox.w;
            karea   = bt ? bar[e] : karea;
        }
    }
    wave_pick_write(sbest, jbest, posbest, kbox, karea, lane,
                    &redk[1][wid], &spayA[1][wid], &spayB[1][wid]);
    __syncthreads();                              // P3

    // first pick (no decay before it)
    int m = 0, prevPos = -1, k = 0;
    float4 pb = make_float4(0.f, 0.f, 0.f, 0.f);
    float  pa = 0.0f, mvS = 0.0f, mvArea = 0.0f;
    float4 mvBox = make_float4(0.f, 0.f, 0.f, 0.f);
    int    mvJ = 0;
    {
        const float4 mA = smovA[1];
        const float4 mB = smovB[1];
        u64 bst = redk[1][0]; float4 pbN = spayA[1][0]; float paN = spayB[1][0];
        #pragma unroll
        for (int w = 1; w < NW; ++w) {
            const u64 o = redk[1][w];
            const bool bt = o > bst;
            bst = bt ? o : bst;
            pbN.x = bt ? spayA[1][w].x : pbN.x;  pbN.y = bt ? spayA[1][w].y : pbN.y;
            pbN.z = bt ? spayA[1][w].z : pbN.z;  pbN.w = bt ? spayA[1][w].w : pbN.w;
            paN   = bt ? spayB[1][w]   : paN;
        }
        if (bst != 0ULL) {
            const int lowb = (int)(u32)bst;
            prevPos = lowb & 0x7FF;
            const int iwin = (N - 1) - ((lowb >> 11) & 0x7FF);
            if (t == 0) sfin[iwin] = __uint_as_float((u32)(bst >> 32) - 1u);
            pb = pbN; pa = paN;
            mvBox = mA; mvArea = mB.x; mvS = mB.y; mvJ = __float_as_int(mB.z);
            m = n0 - 1;
        }
    }

    // ---------------- main loop: decay-by-pick + next argmax ----------------
    while (m > 0) {
        const int par = k & 1;
        sbest = -1.0f; jbest = 0; posbest = 0;
        kbox = make_float4(0.f, 0.f, 0.f, 0.f); karea = 0.0f;
        #pragma unroll
        for (int e = 0; e < E; ++e) {
            const int pos = t + NT * e;
            if (pos < m) {
                if (pos == prevPos) {              // swap-in moved element (regs only)
                    jr[e] = mvJ; sr[e] = mvS;
                    bx1[e] = mvBox.x; by1[e] = mvBox.y;
                    bx2[e] = mvBox.z; by2[e] = mvBox.w;
                    bar[e] = mvArea;
                }
                // byte-identical decay math (absmax==0 in r1-r3)
                const float xx1 = fmaxf(pb.x, bx1[e]);
                const float yy1 = fmaxf(pb.y, by1[e]);
                const float xx2 = fminf(pb.z, bx2[e]);
                const float yy2 = fminf(pb.w, by2[e]);
                const float ww  = fmaxf(xx2 - xx1 + 1.0f, 0.0f);
                const float hh  = fmaxf(yy2 - yy1 + 1.0f, 0.0f);
                const float inter = ww * hh;
                const float iou   = inter / (pa + bar[e] - inter);
                sr[e] *= expf(-(iou * iou) * 2.0f);   // *2 == /SIGMA(0.5) exactly
                if (pos == m - 1) {                // publish next pass's moved payload
                    smovA[par] = make_float4(bx1[e], by1[e], bx2[e], by2[e]);
                    smovB[par] = make_float4(bar[e], sr[e], __int_as_float(jr[e]), 0.0f);
                }
                const bool bt = (sr[e] > sbest) || (sr[e] == sbest && jr[e] < jbest);
                sbest   = bt ? sr[e] : sbest;
                jbest   = bt ? jr[e] : jbest;
                posbest = bt ? pos   : posbest;
                kbox.x  = bt ? bx1[e] : kbox.x;  kbox.y = bt ? by1[e] : kbox.y;
                kbox.z  = bt ? bx2[e] : kbox.z;  kbox.w = bt ? by2[e] : kbox.w;
                karea   = bt ? bar[e] : karea;
            }
        }
        wave_pick_write(sbest, jbest, posbest, kbox, karea, lane,
                        &redk[par][wid], &spayA[par][wid], &spayB[par][wid]);
        __syncthreads();                           // the one barrier per pass

        // single LDS latency stage: all loads issue together, then select
        const float4 mA = smovA[par];
        const float4 mB = smovB[par];
        u64 bst = redk[par][0]; float4 pbN = spayA[par][0]; float paN = spayB[par][0];
        #pragma unroll
        for (int w = 1; w < NW; ++w) {
            const u64 o = redk[par][w];
            const float4 pw = spayA[par][w];
            const float  aw = spayB[par][w];
            const bool bt = o > bst;
            bst = bt ? o : bst;
            pbN.x = bt ? pw.x : pbN.x;  pbN.y = bt ? pw.y : pbN.y;
            pbN.z = bt ? pw.z : pbN.z;  pbN.w = bt ? pw.w : pbN.w;
            paN   = bt ? aw   : paN;
        }
        const int lowb = (int)(u32)bst;            // m>0 => bst != 0
        prevPos = lowb & 0x7FF;
        const int iwin = (N - 1) - ((lowb >> 11) & 0x7FF);
        if (t == 0) sfin[iwin] = __uint_as_float((u32)(bst >> 32) - 1u);
        pb = pbN; pa = paN;
        mvBox = mA; mvArea = mB.x; mvS = mB.y; mvJ = __float_as_int(mB.z);
        --m; ++k;
    }

    __syncthreads();
    // outputs: final (B,N) f32 then keep (B,N) as 0/1 f32. Every valid element
    // is picked exactly once (loop runs n0 passes), so sfin holds finals;
    // invalid entries still hold -1 from the prologue.
    float* of = out + (size_t)b * N;
    float* ok = out + (size_t)B * N + (size_t)b * N;
    #pragma unroll
    for (int e = 0; e < LPT; ++e) {
        const int j = t * LPT + e;
        const float f = sfin[j];
        of[j] = f;
        ok[j] = (f > kThresh) ? 1.0f : 0.0f;
    }
}

extern "C" void kernel_launch(void* const* d_in, const int* in_sizes, int n_in,
                              void* d_out, int out_size, void* d_ws, size_t ws_size,
                              hipStream_t stream) {
    const float* det = (const float*)d_in[0];
    float* out = (float*)d_out;
    const int B = in_sizes[0] / (N * 5);
    hipLaunchKernelGGL(soft_nms_kernel, dim3(B), dim3(NT), 0, stream, det, out, B);
}

// Round 5
// 1000.468 us; speedup vs baseline: 2.0032x; 2.0032x over previous
//
#include <hip/hip_runtime.h>
#include <stdint.h>

static constexpr float kThresh = 0.3f;
static constexpr int N    = 2048;     // detections per batch (fixed)
static constexpr int NT   = 256;      // threads per block (4 waves)
static constexpr int LPT  = N / NT;   // 8 elements loaded/output per thread
static constexpr int NW   = NT / 64;  // 4 waves
static constexpr int KMAX = 8;

using u64 = unsigned long long;
using u32 = unsigned int;

// ---- u64 wave max via DPP on both halves (validated r3/r4) ----
template <int CTRL>
__device__ __forceinline__ u64 dpp_max_u64_step(u64 k) {
    const int lo  = (int)(u32)k;
    const int hi  = (int)(u32)(k >> 32);
    const int mlo = __builtin_amdgcn_update_dpp(lo, lo, CTRL, 0xF, 0xF, false);
    const int mhi = __builtin_amdgcn_update_dpp(hi, hi, CTRL, 0xF, 0xF, false);
    const u64 m   = ((u64)(u32)mhi << 32) | (u32)mlo;
    return (m > k) ? m : k;
}
__device__ __forceinline__ u64 wave_max_u64(u64 k) {
    k = dpp_max_u64_step<0x111>(k);   // row_shr:1
    k = dpp_max_u64_step<0x112>(k);   // row_shr:2
    k = dpp_max_u64_step<0x114>(k);   // row_shr:4
    k = dpp_max_u64_step<0x118>(k);   // row_shr:8
    k = dpp_max_u64_step<0x142>(k);   // row_bcast:15
    k = dpp_max_u64_step<0x143>(k);   // row_bcast:31
    const int lo = __builtin_amdgcn_readlane((int)(u32)k, 63);
    const int hi = __builtin_amdgcn_readlane((int)(u32)(k >> 32), 63);
    return ((u64)(u32)hi << 32) | (u32)lo;
}

struct Pick {            // winner info, uniform across the block
    u32    mid;          // packed id (low key word); 0xFFFFFFFF = "no decay" sentinel
    float4 box;
    float  area;
};

// Decay all K slots by the pending winner (branch-free), kill the winner's
// slot, build keys, return per-thread max key.
// key = (bits(s)+1)<<32 | jp ;  jp = (2047-j)<<21 | t<<13 | e<<10  (unique).
// s>=0 monotone; +1 lets an active score==0.0 beat the empty key 0; equal
// scores -> larger (2047-j) = LOWEST j wins (exactly jnp.argmax).
template <int K>
__device__ __forceinline__ u64 decay_and_keys(
        float (&sr)[KMAX], const float (&x1)[KMAX], const float (&y1)[KMAX],
        const float (&x2)[KMAX], const float (&y2)[KMAX], const float (&ar)[KMAX],
        const u32 (&jp)[KMAX], const Pick& w)
{
    u64 kmax = 0ULL;
    #pragma unroll
    for (int e = 0; e < K; ++e) {
        if (jp[e] == w.mid) sr[e] = -1.0f;       // kill winner (cndmask)
        // byte-identical decay math (absmax==0 across r1-r4)
        const float xx1 = fmaxf(w.box.x, x1[e]);
        const float yy1 = fmaxf(w.box.y, y1[e]);
        const float xx2 = fminf(w.box.z, x2[e]);
        const float yy2 = fminf(w.box.w, y2[e]);
        const float ww  = fmaxf(xx2 - xx1 + 1.0f, 0.0f);
        const float hh  = fmaxf(yy2 - yy1 + 1.0f, 0.0f);
        const float inter = ww * hh;
        const float iou   = inter / (w.area + ar[e] - inter);
        sr[e] *= expf(-(iou * iou) * 2.0f);      // *2 == /SIGMA(0.5) exactly
        // dead slots (sr<0): sentinel box -> iou=0 -> w=1 -> stay negative
        const u64 key = ((u64)(__float_as_uint(sr[e]) + 1u) << 32) | jp[e];
        const u64 kk  = (sr[e] >= 0.0f) ? key : 0ULL;
        if (kk > kmax) kmax = kk;
    }
    return kmax;
}

template <int K>
__device__ __forceinline__ void fill_slots(
        float (&sr)[KMAX], float (&x1)[KMAX], float (&y1)[KMAX],
        float (&x2)[KMAX], float (&y2)[KMAX], float (&ar)[KMAX], u32 (&jp)[KMAX],
        const int* slist, const float* srs, const float4* sbox, const float* sarea,
        int t, int alive)
{
    #pragma unroll
    for (int e = 0; e < K; ++e) {
        const int pos = t + NT * e;
        if (pos < alive) {
            const int j = slist[pos];
            sr[e] = srs[pos];
            const float4 bb = sbox[j];
            x1[e] = bb.x; y1[e] = bb.y; x2[e] = bb.z; y2[e] = bb.w;
            ar[e] = sarea[j];
            jp[e] = ((u32)(N - 1 - j) << 21) | ((u32)t << 13) | ((u32)e << 10);
        } else {                                   // dead: safe no-op defaults
            sr[e] = -1.0f;
            x1[e] = 3.0e38f; y1[e] = 3.0e38f; x2[e] = -3.0e38f; y2[e] = -3.0e38f;
            ar[e] = 1.0f;
            jp[e] = 0x3FFu;                        // low bits set: never matches mid
        }
    }
}

template <int K>
__device__ __forceinline__ void run_tier(
        int& alive, int& k, Pick& w,
        float (&sr)[KMAX], float (&x1)[KMAX], float (&y1)[KMAX],
        float (&x2)[KMAX], float (&y2)[KMAX], float (&ar)[KMAX], u32 (&jp)[KMAX],
        int* slist, float* srs, const float4* sbox, const float* sarea, float* sfin,
        u64 (*redk)[NW], int* swave, int t, int lane, int wid)
{
    const int floorA = (K > 1) ? NT * (K - 1) : 0;
    if (alive <= floorA) return;                  // uniform across block

    fill_slots<K>(sr, x1, y1, x2, y2, ar, jp, slist, srs, sbox, sarea, t, alive);

    const int passes = alive - floorA;
    for (int p = 0; p < passes; ++p) {
        const u64 kmax = decay_and_keys<K>(sr, x1, y1, x2, y2, ar, jp, w);
        const u64 wmax = wave_max_u64(kmax);
        // full keys embed t -> unique across lanes: exactly one writer when wmax!=0
        const bool writer = (wmax != 0ULL) ? (kmax == wmax) : (lane == 0);
        if (writer) redk[k & 1][wid] = wmax;      // parity dbuf: 1 barrier/pass safe
        __syncthreads();
        u64 best = redk[k & 1][0];
        #pragma unroll
        for (int q = 1; q < NW; ++q) {
            const u64 o = redk[k & 1][q];
            if (o > best) best = o;
        }
        const u32 lo   = (u32)best;               // alive>0 => best!=0
        const int winJ = (N - 1) - (int)(lo >> 21);
        w.mid = lo & 0xFFFFFC00u;
        if (t == 0) sfin[winJ] = __uint_as_float((u32)(best >> 32) - 1u);
        w.box  = sbox[winJ];                      // broadcast reads (static data)
        w.area = sarea[winJ];
        ++k;
    }
    alive = floorA;

    if (K > 1) {
        // apply the pending winner, then recompact survivors (alive==256*(K-1))
        (void)decay_and_keys<K>(sr, x1, y1, x2, y2, ar, jp, w);
        w.mid  = 0xFFFFFFFFu;                     // next tier starts with no-op decay
        w.box  = make_float4(3.0e38f, 3.0e38f, -3.0e38f, -3.0e38f);
        w.area = 1.0f;
        int c = 0;
        #pragma unroll
        for (int e = 0; e < K; ++e) c += (sr[e] >= 0.0f) ? 1 : 0;
        int pfx = c;
        #pragma unroll
        for (int d = 1; d < 64; d <<= 1) {
            const int v = __shfl_up(pfx, d, 64);
            if (lane >= d) pfx += v;
        }
        if (lane == 63) swave[wid] = pfx;
        __syncthreads();
        int wbase = 0;
        #pragma unroll
        for (int q = 0; q < NW; ++q)
            if (q < wid) wbase += swave[q];
        int mypos = wbase + (pfx - c);
        #pragma unroll
        for (int e = 0; e < K; ++e) {
            if (sr[e] >= 0.0f) {
                slist[mypos] = (N - 1) - (int)(jp[e] >> 21);
                srs[mypos]   = sr[e];
                ++mypos;
            }
        }
        __syncthreads();
    }
}

__launch_bounds__(NT, 1)
__global__ void soft_nms_kernel(const float* __restrict__ det,
                                float* __restrict__ out, int B)
{
    const int b = blockIdx.x, t = threadIdx.x, lane = t & 63, wid = t >> 6;

    __shared__ float4 sbox[N];      // static after prologue
    __shared__ float  sarea[N];     // static after prologue
    __shared__ float  sfin[N];      // picked values (-1 default)
    __shared__ float  srs[N];       // compacted current scores
    __shared__ int    slist[N];     // compacted indices
    __shared__ int    swave[NW];
    __shared__ u64    redk[2][NW];

    const float* dbase = det + (size_t)b * N * 5;

    // ---------------- prologue: load, classify, compact ----------------
    float scv[LPT]; int lval = 0, c = 0;
    #pragma unroll
    for (int e = 0; e < LPT; ++e) {
        const int j = t * LPT + e;
        const float* p = dbase + (size_t)j * 5;
        const float X1 = p[0], Y1 = p[1], X2 = p[2], Y2 = p[3], SC = p[4];
        sbox[j]  = make_float4(X1, Y1, X2, Y2);
        sarea[j] = (X2 - X1 + 1.0f) * (Y2 - Y1 + 1.0f);
        sfin[j]  = -1.0f;
        scv[e]   = SC;
        const int va = SC > kThresh;
        lval |= va << e; c += va;
    }
    int pfx = c;
    #pragma unroll
    for (int d = 1; d < 64; d <<= 1) {
        const int v = __shfl_up(pfx, d, 64);
        if (lane >= d) pfx += v;
    }
    if (lane == 63) swave[wid] = pfx;
    __syncthreads();
    int wbase = 0, n0 = 0;
    #pragma unroll
    for (int q = 0; q < NW; ++q) {
        const int v = swave[q];
        if (q < wid) wbase += v;
        n0 += v;
    }
    int mypos = wbase + (pfx - c);
    #pragma unroll
    for (int e = 0; e < LPT; ++e)
        if ((lval >> e) & 1) { slist[mypos] = t * LPT + e; srs[mypos] = scv[e]; ++mypos; }
    __syncthreads();

    // ---------------- tiered main loop ----------------
    float sr[KMAX], x1[KMAX], y1[KMAX], x2[KMAX], y2[KMAX], ar[KMAX]; u32 jp[KMAX];
    int alive = n0, k = 0;
    Pick w;
    w.mid  = 0xFFFFFFFFu;
    w.box  = make_float4(3.0e38f, 3.0e38f, -3.0e38f, -3.0e38f);
    w.area = 1.0f;

    run_tier<8>(alive,k,w,sr,x1,y1,x2,y2,ar,jp,slist,srs,sbox,sarea,sfin,redk,swave,t,lane,wid);
    run_tier<7>(alive,k,w,sr,x1,y1,x2,y2,ar,jp,slist,srs,sbox,sarea,sfin,redk,swave,t,lane,wid);
    run_tier<6>(alive,k,w,sr,x1,y1,x2,y2,ar,jp,slist,srs,sbox,sarea,sfin,redk,swave,t,lane,wid);
    run_tier<5>(alive,k,w,sr,x1,y1,x2,y2,ar,jp,slist,srs,sbox,sarea,sfin,redk,swave,t,lane,wid);
    run_tier<4>(alive,k,w,sr,x1,y1,x2,y2,ar,jp,slist,srs,sbox,sarea,sfin,redk,swave,t,lane,wid);
    run_tier<3>(alive,k,w,sr,x1,y1,x2,y2,ar,jp,slist,srs,sbox,sarea,sfin,redk,swave,t,lane,wid);
    run_tier<2>(alive,k,w,sr,x1,y1,x2,y2,ar,jp,slist,srs,sbox,sarea,sfin,redk,swave,t,lane,wid);
    run_tier<1>(alive,k,w,sr,x1,y1,x2,y2,ar,jp,slist,srs,sbox,sarea,sfin,redk,swave,t,lane,wid);

    __syncthreads();
    // outputs: final (B,N) f32 then keep (B,N) as 0/1 f32
    float* of = out + (size_t)b * N;
    float* ok = out + (size_t)B * N + (size_t)b * N;
    #pragma unroll
    for (int e = 0; e < LPT; ++e) {
        const int j = t * LPT + e;
        const float f = sfin[j];
        of[j] = f;
        ok[j] = (f > kThresh) ? 1.0f : 0.0f;
    }
}

extern "C" void kernel_launch(void* const* d_in, const int* in_sizes, int n_in,
                              void* d_out, int out_size, void* d_ws, size_t ws_size,
                              hipStream_t stream) {
    const float* det = (const float*)d_in[0];
    float* out = (float*)d_out;
    const int B = in_sizes[0] / (N * 5);
    hipLaunchKernelGGL(soft_nms_kernel, dim3(B), dim3(NT), 0, stream, det, out, B);
}

// Round 6
// 987.996 us; speedup vs baseline: 2.0285x; 1.0126x over previous
//
#include <hip/hip_runtime.h>
#include <stdint.h>

static constexpr float kThresh = 0.3f;
static constexpr int N    = 2048;     // detections per batch (fixed)
static constexpr int NT   = 256;      // threads per block (4 waves)
static constexpr int LPT  = N / NT;   // 8 elements loaded/output per thread
static constexpr int NW   = NT / 64;  // 4 waves
static constexpr int KMAX = 8;

using u64 = unsigned long long;
using u32 = unsigned int;

// ---- u64 wave max via DPP on both halves (validated r3-r5) ----
template <int CTRL>
__device__ __forceinline__ u64 dpp_max_u64_step(u64 k) {
    const int lo  = (int)(u32)k;
    const int hi  = (int)(u32)(k >> 32);
    const int mlo = __builtin_amdgcn_update_dpp(lo, lo, CTRL, 0xF, 0xF, false);
    const int mhi = __builtin_amdgcn_update_dpp(hi, hi, CTRL, 0xF, 0xF, false);
    const u64 m   = ((u64)(u32)mhi << 32) | (u32)mlo;
    return (m > k) ? m : k;
}
__device__ __forceinline__ u64 wave_max_u64(u64 k) {
    k = dpp_max_u64_step<0x111>(k);   // row_shr:1
    k = dpp_max_u64_step<0x112>(k);   // row_shr:2
    k = dpp_max_u64_step<0x114>(k);   // row_shr:4
    k = dpp_max_u64_step<0x118>(k);   // row_shr:8
    k = dpp_max_u64_step<0x142>(k);   // row_bcast:15
    k = dpp_max_u64_step<0x143>(k);   // row_bcast:31
    const int lo = __builtin_amdgcn_readlane((int)(u32)k, 63);
    const int hi = __builtin_amdgcn_readlane((int)(u32)(k >> 32), 63);
    return ((u64)(u32)hi << 32) | (u32)lo;
}

// Pending picks to apply next pass. Sentinel: mid=0xFFFFFFFF (never matches a
// jp, whose low 10 bits are 0), box=(3e38,3e38,-3e38,-3e38), area=1.0 ->
// inter=0 -> iou=+0 -> expf(-0)=1.0f -> sr*1.0f == sr bit-exactly (no-op).
struct Pick2 {
    u32 mid1, mid2;
    float4 b1, b2;
    float a1, a2;
};
__device__ __forceinline__ void pick2_clear(Pick2& w) {
    w.mid1 = 0xFFFFFFFFu; w.mid2 = 0xFFFFFFFFu;
    w.b1 = make_float4(3.0e38f, 3.0e38f, -3.0e38f, -3.0e38f);
    w.b2 = w.b1;
    w.a1 = 1.0f; w.a2 = 1.0f;
}

// key = (bits(s)+1)<<32 | jp ; jp = (2047-j)<<21 | t<<13 | e<<10 (unique).
// s>=0 monotone; +1 lets active score 0.0 beat empty key 0; equal scores ->
// larger (2047-j) = LOWEST j wins (exactly jnp.argmax). Strict total order.
// Applies the 1-2 pending picks (kill + two sequential decays, reference
// order), rebuilds keys, returns the thread's top-2 keys.
template <int K>
__device__ __forceinline__ void decay_and_keys2(
        float (&sr)[KMAX], const float (&x1)[KMAX], const float (&y1)[KMAX],
        const float (&x2)[KMAX], const float (&y2)[KMAX], const float (&ar)[KMAX],
        const u32 (&jp)[KMAX], const Pick2& w, u64& k1o, u64& k2o)
{
    u64 k1 = 0ULL, k2 = 0ULL;
    #pragma unroll
    for (int e = 0; e < K; ++e) {
        if (jp[e] == w.mid1 || jp[e] == w.mid2) sr[e] = -1.0f;   // kill picked
        {   // decay by pick 1 (byte-identical math, absmax==0 across r1-r5)
            const float xx1 = fmaxf(w.b1.x, x1[e]);
            const float yy1 = fmaxf(w.b1.y, y1[e]);
            const float xx2 = fminf(w.b1.z, x2[e]);
            const float yy2 = fminf(w.b1.w, y2[e]);
            const float ww  = fmaxf(xx2 - xx1 + 1.0f, 0.0f);
            const float hh  = fmaxf(yy2 - yy1 + 1.0f, 0.0f);
            const float inter = ww * hh;
            const float iou   = inter / (w.a1 + ar[e] - inter);
            sr[e] *= expf(-(iou * iou) * 2.0f);   // *2 == /SIGMA(0.5) exactly
        }
        {   // decay by pick 2 (exact no-op when sentinel)
            const float xx1 = fmaxf(w.b2.x, x1[e]);
            const float yy1 = fmaxf(w.b2.y, y1[e]);
            const float xx2 = fminf(w.b2.z, x2[e]);
            const float yy2 = fminf(w.b2.w, y2[e]);
            const float ww  = fmaxf(xx2 - xx1 + 1.0f, 0.0f);
            const float hh  = fmaxf(yy2 - yy1 + 1.0f, 0.0f);
            const float inter = ww * hh;
            const float iou   = inter / (w.a2 + ar[e] - inter);
            sr[e] *= expf(-(iou * iou) * 2.0f);
        }
        const u64 key = ((u64)(__float_as_uint(sr[e]) + 1u) << 32) | jp[e];
        // sign-bit alive test: a dead score underflowing to -0.0 stays dead
        const u64 kk  = (__float_as_int(sr[e]) >= 0) ? key : 0ULL;
        if (kk > k1)      { k2 = k1; k1 = kk; }
        else if (kk > k2) { k2 = kk; }
    }
    k1o = k1; k2o = k2;
}

template <int K>
__device__ __forceinline__ void fill_slots(
        float (&sr)[KMAX], float (&x1)[KMAX], float (&y1)[KMAX],
        float (&x2)[KMAX], float (&y2)[KMAX], float (&ar)[KMAX], u32 (&jp)[KMAX],
        const int* slist, const float* srs, const float4* sbox, int t, int alive)
{
    #pragma unroll
    for (int e = 0; e < K; ++e) {
        const int pos = t + NT * e;
        if (pos < alive) {
            const int j = slist[pos];
            sr[e] = srs[pos];
            const float4 bb = sbox[j];
            x1[e] = bb.x; y1[e] = bb.y; x2[e] = bb.z; y2[e] = bb.w;
            ar[e] = (bb.z - bb.x + 1.0f) * (bb.w - bb.y + 1.0f);  // == prologue formula
            jp[e] = ((u32)(N - 1 - j) << 21) | ((u32)t << 13) | ((u32)e << 10);
        } else {                                   // dead: safe no-op defaults
            sr[e] = -1.0f;
            x1[e] = 3.0e38f; y1[e] = 3.0e38f; x2[e] = -3.0e38f; y2[e] = -3.0e38f;
            ar[e] = 1.0f;
            jp[e] = 0x3FFu;                        // never matches any mid
        }
    }
}

template <int K>
__device__ __forceinline__ void run_tier(
        int& alive, int& k, Pick2& w,
        float (&sr)[KMAX], float (&x1)[KMAX], float (&y1)[KMAX],
        float (&x2)[KMAX], float (&y2)[KMAX], float (&ar)[KMAX], u32 (&jp)[KMAX],
        int* slist, float* srs, const float4* sbox, float* sfin,
        u64 (*redk)[NW][2], int* swave, int t, int lane, int wid)
{
    const int floorA = (K > 1) ? NT * (K - 1) : 0;
    if (alive <= floorA) return;                  // uniform across block

    fill_slots<K>(sr, x1, y1, x2, y2, ar, jp, slist, srs, sbox, t, alive);

    while (alive > floorA) {
        const int par = k & 1;
        u64 k1, k2;
        decay_and_keys2<K>(sr, x1, y1, x2, y2, ar, jp, w, k1, k2);
        // wave top-2: k1-winner lane is unique (keys unique) -> cand trick exact
        const u64 wk1  = wave_max_u64(k1);
        const u64 cand = (k1 == wk1) ? k2 : k1;
        const u64 wk2  = wave_max_u64(cand);
        if (lane == 0) { redk[par][wid][0] = wk1; redk[par][wid][1] = wk2; }
        __syncthreads();                           // the one barrier per pass

        u64 r1[NW], r2[NW];                        // one LDS stage: 8 u64 reads
        #pragma unroll
        for (int q = 0; q < NW; ++q) { r1[q] = redk[par][q][0]; r2[q] = redk[par][q][1]; }
        u64 gw1 = r1[0]; int ws = 0;
        #pragma unroll
        for (int q = 1; q < NW; ++q)
            if (r1[q] > gw1) { gw1 = r1[q]; ws = q; }
        u64 gw2 = 0ULL;
        #pragma unroll
        for (int q = 0; q < NW; ++q) {
            const u64 c = (q == ws) ? r2[q] : r1[q];   // exact global rank-2
            if (c > gw2) gw2 = c;
        }

        const u32 lo1 = (u32)gw1;                  // alive>0 => gw1 != 0
        const int j1  = (N - 1) - (int)(lo1 >> 21);
        const u32 lo2 = (u32)gw2;
        const int j2  = (gw2 != 0ULL) ? ((N - 1) - (int)(lo2 >> 21)) : 0;
        const float4 b1 = sbox[j1];                // broadcast reads, one stage
        const float4 b2 = sbox[j2];
        const float a1 = (b1.z - b1.x + 1.0f) * (b1.w - b1.y + 1.0f);
        const float a2 = (b2.z - b2.x + 1.0f) * (b2.w - b2.y + 1.0f);
        // certificate: picks 1&2 disjoint => pick2 provably == next sequential
        // argmax (decay can only lower keys; w1(i2)=expf(-0)=1.0f exactly)
        const float cx1 = fmaxf(b1.x, b2.x), cy1 = fmaxf(b1.y, b2.y);
        const float cx2 = fminf(b1.z, b2.z), cy2 = fminf(b1.w, b2.w);
        const float cw  = fmaxf(cx2 - cx1 + 1.0f, 0.0f);
        const float ch  = fmaxf(cy2 - cy1 + 1.0f, 0.0f);
        const bool fast = (gw2 != 0ULL) && (cw * ch == 0.0f);

        if (t == 0) {
            sfin[j1] = __uint_as_float((u32)(gw1 >> 32) - 1u);
            if (fast) sfin[j2] = __uint_as_float((u32)(gw2 >> 32) - 1u);
        }
        w.mid1 = lo1; w.b1 = b1; w.a1 = a1;
        if (fast) { w.mid2 = lo2; w.b2 = b2; w.a2 = a2; }
        else {
            w.mid2 = 0xFFFFFFFFu;
            w.b2 = make_float4(3.0e38f, 3.0e38f, -3.0e38f, -3.0e38f);
            w.a2 = 1.0f;
        }
        alive -= fast ? 2 : 1;
        ++k;
    }

    if (K > 1) {
        // apply pending picks, then recompact survivors
        u64 d1, d2;
        decay_and_keys2<K>(sr, x1, y1, x2, y2, ar, jp, w, d1, d2);
        pick2_clear(w);
        int c = 0;
        #pragma unroll
        for (int e = 0; e < K; ++e) c += (__float_as_int(sr[e]) >= 0) ? 1 : 0;
        int pfx = c;
        #pragma unroll
        for (int d = 1; d < 64; d <<= 1) {
            const int v = __shfl_up(pfx, d, 64);
            if (lane >= d) pfx += v;
        }
        if (lane == 63) swave[wid] = pfx;
        __syncthreads();
        int wbase = 0;
        #pragma unroll
        for (int q = 0; q < NW; ++q)
            if (q < wid) wbase += swave[q];
        int mypos = wbase + (pfx - c);
        #pragma unroll
        for (int e = 0; e < K; ++e) {
            if (__float_as_int(sr[e]) >= 0) {
                slist[mypos] = (N - 1) - (int)(jp[e] >> 21);
                srs[mypos]   = sr[e];
                ++mypos;
            }
        }
        __syncthreads();
    }
}

__launch_bounds__(NT, 1)
__global__ void soft_nms_kernel(const float* __restrict__ det,
                                float* __restrict__ out, int B)
{
    const int b = blockIdx.x, t = threadIdx.x, lane = t & 63, wid = t >> 6;

    __shared__ float4 sbox[N];       // static after prologue
    __shared__ float  sfin[N];       // picked values (-1 default)
    __shared__ float  srs[N];        // compacted current scores
    __shared__ int    slist[N];      // compacted indices
    __shared__ int    swave[NW];
    __shared__ u64    redk[2][NW][2];

    const float* dbase = det + (size_t)b * N * 5;

    // ---------------- prologue: load, classify, compact ----------------
    float scv[LPT]; int lval = 0, c = 0;
    #pragma unroll
    for (int e = 0; e < LPT; ++e) {
        const int j = t * LPT + e;
        const float* p = dbase + (size_t)j * 5;
        const float X1 = p[0], Y1 = p[1], X2 = p[2], Y2 = p[3], SC = p[4];
        sbox[j] = make_float4(X1, Y1, X2, Y2);
        sfin[j] = -1.0f;
        scv[e]  = SC;
        const int va = SC > kThresh;
        lval |= va << e; c += va;
    }
    int pfx = c;
    #pragma unroll
    for (int d = 1; d < 64; d <<= 1) {
        const int v = __shfl_up(pfx, d, 64);
        if (lane >= d) pfx += v;
    }
    if (lane == 63) swave[wid] = pfx;
    __syncthreads();
    int wbase = 0, n0 = 0;
    #pragma unroll
    for (int q = 0; q < NW; ++q) {
        const int v = swave[q];
        if (q < wid) wbase += v;
        n0 += v;
    }
    int mypos = wbase + (pfx - c);
    #pragma unroll
    for (int e = 0; e < LPT; ++e)
        if ((lval >> e) & 1) { slist[mypos] = t * LPT + e; srs[mypos] = scv[e]; ++mypos; }
    __syncthreads();

    // ---------------- tiered main loop ----------------
    float sr[KMAX], x1[KMAX], y1[KMAX], x2[KMAX], y2[KMAX], ar[KMAX]; u32 jp[KMAX];
    int alive = n0, k = 0;
    Pick2 w;
    pick2_clear(w);

    run_tier<8>(alive,k,w,sr,x1,y1,x2,y2,ar,jp,slist,srs,sbox,sfin,redk,swave,t,lane,wid);
    run_tier<7>(alive,k,w,sr,x1,y1,x2,y2,ar,jp,slist,srs,sbox,sfin,redk,swave,t,lane,wid);
    run_tier<6>(alive,k,w,sr,x1,y1,x2,y2,ar,jp,slist,srs,sbox,sfin,redk,swave,t,lane,wid);
    run_tier<5>(alive,k,w,sr,x1,y1,x2,y2,ar,jp,slist,srs,sbox,sfin,redk,swave,t,lane,wid);
    run_tier<4>(alive,k,w,sr,x1,y1,x2,y2,ar,jp,slist,srs,sbox,sfin,redk,swave,t,lane,wid);
    run_tier<3>(alive,k,w,sr,x1,y1,x2,y2,ar,jp,slist,srs,sbox,sfin,redk,swave,t,lane,wid);
    run_tier<2>(alive,k,w,sr,x1,y1,x2,y2,ar,jp,slist,srs,sbox,sfin,redk,swave,t,lane,wid);
    run_tier<1>(alive,k,w,sr,x1,y1,x2,y2,ar,jp,slist,srs,sbox,sfin,redk,swave,t,lane,wid);

    __syncthreads();
    // outputs: final (B,N) f32 then keep (B,N) as 0/1 f32
    float* of = out + (size_t)b * N;
    float* ok = out + (size_t)B * N + (size_t)b * N;
    #pragma unroll
    for (int e = 0; e < LPT; ++e) {
        const int j = t * LPT + e;
        const float f = sfin[j];
        of[j] = f;
        ok[j] = (f > kThresh) ? 1.0f : 0.0f;
    }
}

extern "C" void kernel_launch(void* const* d_in, const int* in_sizes, int n_in,
                              void* d_out, int out_size, void* d_ws, size_t ws_size,
                              hipStream_t stream) {
    const float* det = (const float*)d_in[0];
    float* out = (float*)d_out;
    const int B = in_sizes[0] / (N * 5);
    hipLaunchKernelGGL(soft_nms_kernel, dim3(B), dim3(NT), 0, stream, det, out, B);
}